// Round 15
// baseline (131.864 us; speedup 1.0000x reference)
//
#include <hip/hip_runtime.h>
#include <hip/hip_bf16.h>

#define VOCABN 50000
#define BN 128
#define CN 5
#define HN 50
#define LN 32
#define DN 300
#define DP 320     // padded K
#define KNN 20

typedef __bf16    bf16x8 __attribute__((ext_vector_type(8)));
typedef float     f32x4  __attribute__((ext_vector_type(4)));
typedef float     f32x2  __attribute__((ext_vector_type(2)));
typedef ushort    u16x8  __attribute__((ext_vector_type(8)));

#if __has_builtin(__builtin_amdgcn_exp2f)
#define FEXP2 __builtin_amdgcn_exp2f
#else
#define FEXP2 exp2f
#endif
#if __has_builtin(__builtin_amdgcn_logf)
#define FLOG2 __builtin_amdgcn_logf
#else
#define FLOG2 log2f
#endif

#define LOG2E 1.4426950408889634f
#define LN2F  0.6931471805599453f

// ---------------- kernel 1: normalize vocab -> bf16 table, wave-per-row (R11-proven) ----------------
__global__ __launch_bounds__(256) void knorm_embed2(const float* __restrict__ emb,
                                                    ushort* __restrict__ tabo) {
    const int t    = threadIdx.x;
    const int lane = t & 63;
    const int w    = t >> 6;
    const int v    = blockIdx.x * 4 + w;          // grid 12500 x 4 waves
    const float* row = emb + (size_t)v * DN;
    const float4* r4 = (const float4*)row;

    float4 x = r4[lane];
    float ss = x.x * x.x + x.y * x.y + x.z * x.z + x.w * x.w;
    if (lane < 11) {
        float4 y = r4[64 + lane];
        ss += y.x * y.x + y.y * y.y + y.z * y.z + y.w * y.w;
    }
    #pragma unroll
    for (int off = 32; off; off >>= 1) ss += __shfl_xor(ss, off);
    const float scale = 1.0f / fmaxf(sqrtf(ss), 1e-8f);

    if (lane < 40) {
        u16x8 u;
        #pragma unroll
        for (int j = 0; j < 8; ++j) {
            int e = lane * 8 + j;
            float f = (e < DN) ? row[e] * scale : 0.f;
            __hip_bfloat16 h = __float2bfloat16(f);
            u[j] = *(ushort*)&h;
        }
        *(u16x8*)(tabo + (size_t)v * DP + lane * 8) = u;
    }
}

// ---------------- kernel 2: fused GEMM + pooling, 2-phase double-buffered BK=32 ----------------
// 3200 blocks (b x 25 h-pairs), 320 threads. Slice buffers: [row][40 ushorts] = 80B rows
// (64B data + 16B pad): bank offsets r*20 mod 32 pairwise >=4 apart -> <=2-way (free),
// no swizzle. Double-buffered; gathers for slice ss+1 issue during compute of ss.
__global__ __launch_bounds__(320, 4) void knrm_fused6(const int* __restrict__ cand,
                                                      const int* __restrict__ clik,
                                                      const ushort* __restrict__ tab,
                                                      const float* __restrict__ ltr_w,
                                                      float* __restrict__ score) {
    __shared__ __align__(16) ushort Abuf[2][160 * 40];  // 2 x 12.8 KB
    __shared__ __align__(16) ushort Bbuf[2][64 * 40];   // 2 x 5.12 KB
    __shared__ int tokA[160];
    __shared__ int tokB[64];

    const int t    = threadIdx.x;
    const int lane = t & 63;
    const int w    = t >> 6;          // wave 0..4 == candidate c
    // T1: bijective XCD swizzle (grid 3200 = 8 x 400); 25 same-b blocks land co-XCD
    const int bid  = (blockIdx.x & 7) * 400 + (blockIdx.x >> 3);
    const int b    = bid / 25;
    const int hg   = bid % 25;        // h-pair group: h = hg*2, hg*2+1
    const int h0   = hg * 2;

    if (t < 160)      tokA[t] = cand[b * (CN * LN) + t];
    else if (t < 224) tokB[t - 160] = clik[b * (HN * LN) + h0 * LN + (t - 160)];
    __syncthreads();

    const int m15 = lane & 15;
    const int g4  = lane >> 4;

    // hoisted staging geometry (BK=32: 4 chunks of 16B per row per slice)
    // A: 640 chunks / 320 thr = 2 each; B: 256 chunks, t<256 = 1 each.
    const char* srcA[2]; int dstA[2];
    #pragma unroll
    for (int it = 0; it < 2; ++it) {
        int cid = it * 320 + t, row = cid >> 2, c = cid & 3;
        srcA[it] = (const char*)tab + (size_t)tokA[row] * (DP * 2) + c * 16;
        dstA[it] = row * 80 + c * 16;
    }
    const char* srcB; int dstB;
    {
        int tb = (t < 256) ? t : (t - 64);
        int row = tb >> 2, c = tb & 3;
        srcB = (const char*)tab + (size_t)tokB[row] * (DP * 2) + c * 16;
        dstB = row * 80 + c * 16;
    }

    f32x4 acc[2][4];
    #pragma unroll
    for (int at = 0; at < 2; ++at)
        #pragma unroll
        for (int jg = 0; jg < 4; ++jg)
            acc[at][jg] = (f32x4){0.f, 0.f, 0.f, 0.f};

    // prologue: stage slice 0 into buf 0
    {
        int4 a0 = *(const int4*)(srcA[0]);
        int4 a1 = *(const int4*)(srcA[1]);
        int4 b0; if (t < 256) b0 = *(const int4*)(srcB);
        *(int4*)((char*)&Abuf[0][0] + dstA[0]) = a0;
        *(int4*)((char*)&Abuf[0][0] + dstA[1]) = a1;
        if (t < 256) *(int4*)((char*)&Bbuf[0][0] + dstB) = b0;
    }
    __syncthreads();

    #pragma unroll 2
    for (int ss = 0; ss < 10; ++ss) {         // 10 K-slices of 32
        const ushort* A = &Abuf[ss & 1][0];
        const ushort* B = &Bbuf[ss & 1][0];

        // issue next-slice gathers early (consumed after the MFMA phase)
        int4 a0, a1, b0;
        if (ss < 9) {
            const int so = (ss + 1) * 64;
            a0 = *(const int4*)(srcA[0] + so);
            a1 = *(const int4*)(srcA[1] + so);
            if (t < 256) b0 = *(const int4*)(srcB + so);
        }

        // compute slice ss: 6 ds_read_b128 + 8 MFMA
        bf16x8 af0 = *(const bf16x8*)((const char*)A + (w * 32 + m15) * 80 + g4 * 16);
        bf16x8 af1 = *(const bf16x8*)((const char*)A + (w * 32 + 16 + m15) * 80 + g4 * 16);
        #pragma unroll
        for (int jg = 0; jg < 4; ++jg) {
            bf16x8 bf = *(const bf16x8*)((const char*)B + (jg * 16 + m15) * 80 + g4 * 16);
            acc[0][jg] = __builtin_amdgcn_mfma_f32_16x16x32_bf16(af0, bf, acc[0][jg], 0, 0, 0);
            acc[1][jg] = __builtin_amdgcn_mfma_f32_16x16x32_bf16(af1, bf, acc[1][jg], 0, 0, 0);
        }

        // write next slice into the other buffer (data arrived during MFMA)
        if (ss < 9) {
            char* An = (char*)&Abuf[(ss + 1) & 1][0];
            char* Bn = (char*)&Bbuf[(ss + 1) & 1][0];
            *(int4*)(An + dstA[0]) = a0;
            *(int4*)(An + dstA[1]) = a1;
            if (t < 256) *(int4*)(Bn + dstB) = b0;
            __syncthreads();                  // publish ss+1 / free buf[ss&1]
        }
        // ss==9: no barrier — fall straight into wave-private pooling
    }

    // ---- fused pooling (R14 packed version, wave-private) ----
    // simbuf aliases Abuf[0]: last slice computed from buf[1]; nobody touches Abuf[0].
    const float C1   = 10.0f * LOG2E;
    const float C2   = -50.0f * LOG2E;
    const float AK19 = 849.3218002880191f;  // sqrt(LOG2E / (2*0.001^2))
    static const float CkT[10] = {          // e^{-m^2/2}; unrolled j folds to immediates
        1.0f, 0.6065306597126334f, 0.1353352832366127f, 0.011108996538242306f,
        3.3546262790251185e-4f, 3.7266531720786709e-6f, 1.5229979744712628e-8f,
        2.2897348456191135e-11f, 1.2664165549094176e-14f, 2.576757109154981e-18f };

    float* sb = (float*)&Abuf[0][0] + w * (16 * 33);  // [16][33] f32, wave-private
    const float* sp0 = sb + (lane >> 2) * 33 + (lane & 3) * 8;
    float res = 0.f;

    #pragma unroll
    for (int hl = 0; hl < 2; ++hl) {
        const float* wrow = ltr_w + (h0 + hl) * KNN;
        #pragma unroll
        for (int at = 0; at < 2; ++at) {
            // dump tile: C/D col=lane&15, row=(lane>>4)*4+r [m89-verified]
            #pragma unroll
            for (int r = 0; r < 4; ++r) {
                sb[(g4 * 4 + r) * 33 + m15]      = acc[at][hl * 2][r];
                sb[(g4 * 4 + r) * 33 + 16 + m15] = acc[at][hl * 2 + 1][r];
            }
            // wave-internal lgkmcnt ordering makes writes visible below

            f32x2 Qp[9];                          // Qp[j-1] = {Q[9+j], Q[9-j]}
            #pragma unroll
            for (int j = 0; j < 9; ++j) Qp[j] = (f32x2){0.f, 0.f};
            float Q9 = 0.f, Q19 = 0.f;

            #pragma unroll
            for (int e = 0; e < 8; ++e) {
                float s  = sp0[e];
                float cs = C1 * s;
                float tt = FEXP2(cs);
                float uu = FEXP2(-cs);
                float e0 = FEXP2(C2 * (s * s));
                Q9 += e0;
                f32x2 tu = {tt, uu};
                f32x2 pm = {e0, e0};
                #pragma unroll
                for (int j = 0; j < 9; ++j) { pm *= tu; Qp[j] += pm; }  // v_pk_mul/add
                float d = fmaf(s, AK19, -AK19);   // (s-1)*AK19
                Q19 += FEXP2(-(d * d));           // sharp sigma=0.001 kernel
            }
            // 4-lane row reduce (DPP quad perms), per component
            #pragma unroll
            for (int j = 0; j < 9; ++j) {
                Qp[j].x += __shfl_xor(Qp[j].x, 1); Qp[j].x += __shfl_xor(Qp[j].x, 2);
                Qp[j].y += __shfl_xor(Qp[j].y, 1); Qp[j].y += __shfl_xor(Qp[j].y, 2);
            }
            Q9  += __shfl_xor(Q9, 1);  Q9  += __shfl_xor(Q9, 2);
            Q19 += __shfl_xor(Q19, 1); Q19 += __shfl_xor(Q19, 2);

            // weighted log-sum; j unrolled -> CkT immediates. k=9+j (+), k=9-j (-)
            float rs = wrow[9] * FLOG2(fmaxf(Q9, 1e-10f));
            #pragma unroll
            for (int j = 1; j <= 9; ++j) {
                rs += wrow[9 + j] * FLOG2(fmaxf(Qp[j - 1].x * CkT[j], 1e-10f));
                rs += wrow[9 - j] * FLOG2(fmaxf(Qp[j - 1].y * CkT[j], 1e-10f));
            }
            rs += wrow[19] * FLOG2(fmaxf(Q19, 1e-10f));
            res += rs;
        }
    }

    // each row counted by 4 lanes -> x0.25; log2 -> ln
    res *= 0.25f * LN2F;
    #pragma unroll
    for (int off = 32; off; off >>= 1) res += __shfl_xor(res, off);
    if (lane == 0) atomicAdd(&score[b * CN + w], res);
}

// ---------------- kernel 3: log_softmax over C (ltr_b cancels) ----------------
__global__ __launch_bounds__(128) void knrm_final(const float* __restrict__ score,
                                                  float* __restrict__ out) {
    int b = threadIdx.x;
    if (b < BN) {
        float s[CN];
        float m = -1e30f;
        #pragma unroll
        for (int c = 0; c < CN; ++c) { s[c] = score[b * CN + c]; m = fmaxf(m, s[c]); }
        float sum = 0.f;
        #pragma unroll
        for (int c = 0; c < CN; ++c) sum += FEXP2((s[c] - m) * LOG2E);
        float lse = m + FLOG2(sum) * LN2F;
        #pragma unroll
        for (int c = 0; c < CN; ++c) out[b * CN + c] = s[c] - lse;
    }
}

extern "C" void kernel_launch(void* const* d_in, const int* in_sizes, int n_in,
                              void* d_out, int out_size, void* d_ws, size_t ws_size,
                              hipStream_t stream) {
    const int*   cand  = (const int*)d_in[0];   // [B,C,L]
    const int*   clik  = (const int*)d_in[1];   // [B,H,L]
    const float* emb   = (const float*)d_in[2]; // [VOCAB,D]
    const float* ltr_w = (const float*)d_in[3]; // [1,H*KN]
    float* out = (float*)d_out;

    const size_t TAB_B = (size_t)VOCABN * DP * 2;   // 32,000,000

    ushort* tab  = (ushort*)d_ws;
    float*  scre = (float*)((char*)d_ws + TAB_B);

    hipMemsetAsync(scre, 0, BN * CN * sizeof(float), stream);
    knorm_embed2<<<VOCABN / 4, 256, 0, stream>>>(emb, tab);
    knrm_fused6<<<BN * 25, 320, 0, stream>>>(cand, clik, tab, ltr_w, scre);
    knrm_final<<<1, 128, 0, stream>>>(scre, out);
}

// Round 16
// 129.611 us; speedup vs baseline: 1.0174x; 1.0174x over previous
//
#include <hip/hip_runtime.h>
#include <hip/hip_bf16.h>

#define VOCABN 50000
#define BN 128
#define CN 5
#define HN 50
#define LN 32
#define DN 300
#define DP 320     // padded K
#define KNN 20

typedef __bf16    bf16x8 __attribute__((ext_vector_type(8)));
typedef float     f32x4  __attribute__((ext_vector_type(4)));
typedef float     f32x2  __attribute__((ext_vector_type(2)));
typedef ushort    u16x8  __attribute__((ext_vector_type(8)));

#if __has_builtin(__builtin_amdgcn_exp2f)
#define FEXP2 __builtin_amdgcn_exp2f
#else
#define FEXP2 exp2f
#endif
#if __has_builtin(__builtin_amdgcn_logf)
#define FLOG2 __builtin_amdgcn_logf
#else
#define FLOG2 log2f
#endif

#define LOG2E 1.4426950408889634f
#define LN2F  0.6931471805599453f

// ---------------- kernel 1: normalize vocab -> bf16 table, wave-per-row (R11-proven) ----------------
__global__ __launch_bounds__(256) void knorm_embed2(const float* __restrict__ emb,
                                                    ushort* __restrict__ tabo) {
    const int t    = threadIdx.x;
    const int lane = t & 63;
    const int w    = t >> 6;
    const int v    = blockIdx.x * 4 + w;          // grid 12500 x 4 waves
    const float* row = emb + (size_t)v * DN;
    const float4* r4 = (const float4*)row;

    float4 x = r4[lane];
    float ss = x.x * x.x + x.y * x.y + x.z * x.z + x.w * x.w;
    if (lane < 11) {
        float4 y = r4[64 + lane];
        ss += y.x * y.x + y.y * y.y + y.z * y.z + y.w * y.w;
    }
    #pragma unroll
    for (int off = 32; off; off >>= 1) ss += __shfl_xor(ss, off);
    const float scale = 1.0f / fmaxf(sqrtf(ss), 1e-8f);

    if (lane < 40) {
        u16x8 u;
        #pragma unroll
        for (int j = 0; j < 8; ++j) {
            int e = lane * 8 + j;
            float f = (e < DN) ? row[e] * scale : 0.f;
            __hip_bfloat16 h = __float2bfloat16(f);
            u[j] = *(ushort*)&h;
        }
        *(u16x8*)(tabo + (size_t)v * DP + lane * 8) = u;
    }
}

// Paired-row LDS layout (BK=32): LDS row R=ar>>1 (128B) holds A-rows 2R (slots 0-3) and
// 2R+1 (slots 4-7); slot XOR'd by R&7 (R6-proven conflict pattern: 8 spans x 2 lanes/group).
__device__ __forceinline__ int paddr(int row, int c) {
    return ((row >> 1) << 7) + ((((c + ((row & 1) << 2))) ^ ((row >> 1) & 7)) << 4);
}
__device__ __forceinline__ bf16x8 ldP(const ushort* buf, int row, int c) {
    return *(const bf16x8*)((const char*)buf + paddr(row, c));
}

// ---------------- kernel 2: fused GEMM + pooling, double-buffered BK=32, paired-row XOR LDS ----------------
// 3200 blocks (b x 25 h-pairs), 320 threads, ~29 KB LDS, acc[2][4]=32 regs.
__global__ __launch_bounds__(320, 4) void knrm_fused7(const int* __restrict__ cand,
                                                      const int* __restrict__ clik,
                                                      const ushort* __restrict__ tab,
                                                      const float* __restrict__ ltr_w,
                                                      float* __restrict__ score) {
    __shared__ __align__(16) ushort Abuf[2][80 * 64];   // 2 x 10 KB (160 A-rows paired)
    __shared__ __align__(16) ushort Bbuf[2][32 * 64];   // 2 x 4 KB  (64 B-rows paired)
    __shared__ int tokA[160];
    __shared__ int tokB[64];

    const int t    = threadIdx.x;
    const int lane = t & 63;
    const int w    = t >> 6;          // wave 0..4 == candidate c
    // T1: bijective XCD swizzle (grid 3200 = 8 x 400); 25 same-b blocks land co-XCD
    const int bid  = (blockIdx.x & 7) * 400 + (blockIdx.x >> 3);
    const int b    = bid / 25;
    const int hg   = bid % 25;        // h-pair group: h = hg*2, hg*2+1
    const int h0   = hg * 2;

    if (t < 160)      tokA[t] = cand[b * (CN * LN) + t];
    else if (t < 224) tokB[t - 160] = clik[b * (HN * LN) + h0 * LN + (t - 160)];
    __syncthreads();

    const int m15 = lane & 15;
    const int g4  = lane >> 4;

    // hoisted staging geometry (BK=32: 4 x 16B chunks per row per slice)
    // A: 640 chunks / 320 thr = 2 each; B: 256 chunks, t<256 = 1 each.
    const char* srcA[2]; int dstA[2];
    #pragma unroll
    for (int it = 0; it < 2; ++it) {
        int cid = it * 320 + t, ar = cid >> 2, c = cid & 3;
        srcA[it] = (const char*)tab + (size_t)tokA[ar] * (DP * 2) + c * 16;
        dstA[it] = paddr(ar, c);
    }
    const char* srcB; int dstB;
    {
        int tb = (t < 256) ? t : (t - 64);
        int ar = tb >> 2, c = tb & 3;
        srcB = (const char*)tab + (size_t)tokB[ar] * (DP * 2) + c * 16;
        dstB = paddr(ar, c);
    }

    f32x4 acc[2][4];
    #pragma unroll
    for (int at = 0; at < 2; ++at)
        #pragma unroll
        for (int jg = 0; jg < 4; ++jg)
            acc[at][jg] = (f32x4){0.f, 0.f, 0.f, 0.f};

    // prologue: stage slice 0 into buf 0
    {
        int4 a0 = *(const int4*)(srcA[0]);
        int4 a1 = *(const int4*)(srcA[1]);
        int4 b0; if (t < 256) b0 = *(const int4*)(srcB);
        *(int4*)((char*)&Abuf[0][0] + dstA[0]) = a0;
        *(int4*)((char*)&Abuf[0][0] + dstA[1]) = a1;
        if (t < 256) *(int4*)((char*)&Bbuf[0][0] + dstB) = b0;
    }
    __syncthreads();

    #pragma unroll 2
    for (int ss = 0; ss < 10; ++ss) {         // 10 K-slices of 32
        const ushort* A = &Abuf[ss & 1][0];
        const ushort* B = &Bbuf[ss & 1][0];

        // issue next-slice gathers early (consumed after the MFMA phase)
        int4 a0, a1, b0;
        if (ss < 9) {
            const int so = (ss + 1) * 64;
            a0 = *(const int4*)(srcA[0] + so);
            a1 = *(const int4*)(srcA[1] + so);
            if (t < 256) b0 = *(const int4*)(srcB + so);
        }

        // compute slice ss: 6 ds_read_b128 + 8 MFMA (paired-row XOR addressing)
        bf16x8 af0 = ldP(A, w * 32 + m15,      g4);
        bf16x8 af1 = ldP(A, w * 32 + 16 + m15, g4);
        #pragma unroll
        for (int jg = 0; jg < 4; ++jg) {
            bf16x8 bf = ldP(B, jg * 16 + m15, g4);
            acc[0][jg] = __builtin_amdgcn_mfma_f32_16x16x32_bf16(af0, bf, acc[0][jg], 0, 0, 0);
            acc[1][jg] = __builtin_amdgcn_mfma_f32_16x16x32_bf16(af1, bf, acc[1][jg], 0, 0, 0);
        }

        // write next slice into the other buffer (data arrived during MFMA)
        if (ss < 9) {
            char* An = (char*)&Abuf[(ss + 1) & 1][0];
            char* Bn = (char*)&Bbuf[(ss + 1) & 1][0];
            *(int4*)(An + dstA[0]) = a0;
            *(int4*)(An + dstA[1]) = a1;
            if (t < 256) *(int4*)(Bn + dstB) = b0;
            __syncthreads();                  // publish ss+1 / free buf[ss&1]
        }
        // ss==9: no barrier — fall straight into wave-private pooling
    }

    // ---- fused pooling (R14 packed version, wave-private, no final barrier) ----
    // simbuf aliasing (race-free): waves 0-3 use Abuf[0], wave 4 uses Bbuf[0] — both
    // last read at the ss=8 barrier; slice 9 reads only buf[1].
    const float C1   = 10.0f * LOG2E;
    const float C2   = -50.0f * LOG2E;
    const float AK19 = 849.3218002880191f;  // sqrt(LOG2E / (2*0.001^2))
    static const float CkT[10] = {          // e^{-m^2/2}; unrolled j folds to immediates
        1.0f, 0.6065306597126334f, 0.1353352832366127f, 0.011108996538242306f,
        3.3546262790251185e-4f, 3.7266531720786709e-6f, 1.5229979744712628e-8f,
        2.2897348456191135e-11f, 1.2664165549094176e-14f, 2.576757109154981e-18f };

    float* sb = (w < 4) ? ((float*)&Abuf[0][0] + w * (16 * 33))
                        : ((float*)&Bbuf[0][0]);          // [16][33] f32, wave-private
    const float* sp0 = sb + (lane >> 2) * 33 + (lane & 3) * 8;
    float res = 0.f;

    #pragma unroll
    for (int hl = 0; hl < 2; ++hl) {
        const float* wrow = ltr_w + (h0 + hl) * KNN;
        #pragma unroll
        for (int at = 0; at < 2; ++at) {
            // dump tile: C/D col=lane&15, row=(lane>>4)*4+r [m89-verified]
            #pragma unroll
            for (int r = 0; r < 4; ++r) {
                sb[(g4 * 4 + r) * 33 + m15]      = acc[at][hl * 2][r];
                sb[(g4 * 4 + r) * 33 + 16 + m15] = acc[at][hl * 2 + 1][r];
            }
            // wave-internal lgkmcnt ordering makes writes visible below

            f32x2 Qp[9];                          // Qp[j-1] = {Q[9+j], Q[9-j]}
            #pragma unroll
            for (int j = 0; j < 9; ++j) Qp[j] = (f32x2){0.f, 0.f};
            float Q9 = 0.f, Q19 = 0.f;

            #pragma unroll
            for (int e = 0; e < 8; ++e) {
                float s  = sp0[e];
                float cs = C1 * s;
                float tt = FEXP2(cs);
                float uu = FEXP2(-cs);
                float e0 = FEXP2(C2 * (s * s));
                Q9 += e0;
                f32x2 tu = {tt, uu};
                f32x2 pm = {e0, e0};
                #pragma unroll
                for (int j = 0; j < 9; ++j) { pm *= tu; Qp[j] += pm; }  // v_pk_mul/add
                float d = fmaf(s, AK19, -AK19);   // (s-1)*AK19
                Q19 += FEXP2(-(d * d));           // sharp sigma=0.001 kernel
            }
            // 4-lane row reduce (DPP quad perms), per component
            #pragma unroll
            for (int j = 0; j < 9; ++j) {
                Qp[j].x += __shfl_xor(Qp[j].x, 1); Qp[j].x += __shfl_xor(Qp[j].x, 2);
                Qp[j].y += __shfl_xor(Qp[j].y, 1); Qp[j].y += __shfl_xor(Qp[j].y, 2);
            }
            Q9  += __shfl_xor(Q9, 1);  Q9  += __shfl_xor(Q9, 2);
            Q19 += __shfl_xor(Q19, 1); Q19 += __shfl_xor(Q19, 2);

            // weighted log-sum; j unrolled -> CkT immediates. k=9+j (+), k=9-j (-)
            float rs = wrow[9] * FLOG2(fmaxf(Q9, 1e-10f));
            #pragma unroll
            for (int j = 1; j <= 9; ++j) {
                rs += wrow[9 + j] * FLOG2(fmaxf(Qp[j - 1].x * CkT[j], 1e-10f));
                rs += wrow[9 - j] * FLOG2(fmaxf(Qp[j - 1].y * CkT[j], 1e-10f));
            }
            rs += wrow[19] * FLOG2(fmaxf(Q19, 1e-10f));
            res += rs;
        }
    }

    // each row counted by 4 lanes -> x0.25; log2 -> ln
    res *= 0.25f * LN2F;
    #pragma unroll
    for (int off = 32; off; off >>= 1) res += __shfl_xor(res, off);
    if (lane == 0) atomicAdd(&score[b * CN + w], res);
}

// ---------------- kernel 3: log_softmax over C (ltr_b cancels) ----------------
__global__ __launch_bounds__(128) void knrm_final(const float* __restrict__ score,
                                                  float* __restrict__ out) {
    int b = threadIdx.x;
    if (b < BN) {
        float s[CN];
        float m = -1e30f;
        #pragma unroll
        for (int c = 0; c < CN; ++c) { s[c] = score[b * CN + c]; m = fmaxf(m, s[c]); }
        float sum = 0.f;
        #pragma unroll
        for (int c = 0; c < CN; ++c) sum += FEXP2((s[c] - m) * LOG2E);
        float lse = m + FLOG2(sum) * LN2F;
        #pragma unroll
        for (int c = 0; c < CN; ++c) out[b * CN + c] = s[c] - lse;
    }
}

extern "C" void kernel_launch(void* const* d_in, const int* in_sizes, int n_in,
                              void* d_out, int out_size, void* d_ws, size_t ws_size,
                              hipStream_t stream) {
    const int*   cand  = (const int*)d_in[0];   // [B,C,L]
    const int*   clik  = (const int*)d_in[1];   // [B,H,L]
    const float* emb   = (const float*)d_in[2]; // [VOCAB,D]
    const float* ltr_w = (const float*)d_in[3]; // [1,H*KN]
    float* out = (float*)d_out;

    const size_t TAB_B = (size_t)VOCABN * DP * 2;   // 32,000,000

    ushort* tab  = (ushort*)d_ws;
    float*  scre = (float*)((char*)d_ws + TAB_B);

    hipMemsetAsync(scre, 0, BN * CN * sizeof(float), stream);
    knorm_embed2<<<VOCABN / 4, 256, 0, stream>>>(emb, tab);
    knrm_fused7<<<BN * 25, 320, 0, stream>>>(cand, clik, tab, ltr_w, scre);
    knrm_final<<<1, 128, 0, stream>>>(scre, out);
}